// Round 16
// baseline (225.797 us; speedup 1.0000x reference)
//
#include <hip/hip_runtime.h>
#include <hip/hip_bf16.h>
#include <stdint.h>

// ---- problem constants ----
#define BDIM 2
#define SDIM 2048
#define HID 2048
#define NH 16
#define NKV 4
#define HD 128
#define QSZ 2048
#define KVSZ 512
#define QKVW 3072          // QSZ + 2*KVSZ
#define TOK (BDIM*SDIM)    // 4096

typedef __attribute__((ext_vector_type(8))) short bf16x8;
typedef __attribute__((ext_vector_type(4))) float f32x4;
typedef __attribute__((ext_vector_type(16))) float f32x16;

__device__ __forceinline__ short f2bf(float f) {
  return (short)__bfloat16_as_ushort(__float2bfloat16(f));   // RNE; pairs fuse to v_cvt_pk_bf16_f32
}

// 2^x via the HW transcendental (no __exp2f in this toolchain's headers)
__device__ __forceinline__ float exp2_fast(float x) {
  float r;
  asm("v_exp_f32 %0, %1" : "=v"(r) : "v"(x));
  return r;
}

// sin/cos with input in REVOLUTIONS (v_sin/v_cos native domain; fract-reduce first)
__device__ __forceinline__ void sincos_rev(float rev, float* sn, float* cs) {
  float fr, s, c;
  asm("v_fract_f32 %0, %1" : "=v"(fr) : "v"(rev));
  asm("v_sin_f32 %0, %1" : "=v"(s) : "v"(fr));
  asm("v_cos_f32 %0, %1" : "=v"(c) : "v"(fr));
  *sn = s; *cs = c;
}

// XCD-aware block swizzle (T1, m157 form; requires nwg % 8 == 0)
__device__ __forceinline__ int xcd_swz(int orig, int nwg) {
  int cpx = nwg >> 3;
  return (orig & 7) * cpx + (orig >> 3);
}

__device__ __forceinline__ void gload_lds16(const void* g, void* lds) {
  __builtin_amdgcn_global_load_lds(
      (const __attribute__((address_space(1))) void*)g,
      (__attribute__((address_space(3))) void*)lds, 16, 0, 0);
}

// ---- fused prep: hidden f32->bf16 (blocks 0..8191), w_qkv transpose
// (blocks 8192..9727, 48x32 tiles), w_o transpose (blocks 9728..10751, 32x32) ----
__global__ __launch_bounds__(256) void k_prep(const float* __restrict__ hidden,
                                              const float* __restrict__ w_qkv,
                                              const float* __restrict__ w_o,
                                              short* __restrict__ X,
                                              short* __restrict__ WqkvT,
                                              short* __restrict__ WoT) {
  __shared__ short tile[64][65];
  const int bid = blockIdx.x;
  const int t = threadIdx.x;
  if (bid < 8192) {
    int i = (bid * 256 + t) * 4;
    float4 v = *(const float4*)(hidden + i);
    short4 o; o.x = f2bf(v.x); o.y = f2bf(v.y); o.z = f2bf(v.z); o.w = f2bf(v.w);
    *(short4*)(X + i) = o;
    return;
  }
  const float* in; short* out; int R, C, bx, by;
  if (bid < 9728) {
    int tt = bid - 8192; in = w_qkv; out = WqkvT; R = HID; C = QKVW;
    bx = tt % 48; by = tt / 48;
  } else {
    int tt = bid - 9728; in = w_o; out = WoT; R = QSZ; C = HID;
    bx = tt & 31; by = tt >> 5;
  }
  int k0 = by * 64, n0 = bx * 64;
#pragma unroll
  for (int i = 0; i < 16; ++i) {
    int idx = i * 256 + t;
    int kk = idx >> 6, nn = idx & 63;
    tile[kk][nn] = f2bf(in[(size_t)(k0 + kk) * C + n0 + nn]);
  }
  __syncthreads();
#pragma unroll
  for (int i = 0; i < 16; ++i) {
    int idx = i * 256 + t;
    int nn = idx >> 6, kk = idx & 63;
    out[(size_t)(n0 + nn) * R + k0 + kk] = tile[kk][nn];
  }
}

// ---- bf16 GEMM: C[M][N] f32 = A[M][K] * Bt[N][K]^T  (m97 structure, BK=64) ----
// BK=64 halves the barrier-drain count vs BK=32 (32 K-steps at K=2048).
// 1D grid, XCD-swizzled. Staging swizzle: 8 chunks/row, src chunk cc^(r&7),
// linear LDS dest (rule #21); read chunk (kk*4+g)^(row&7).
__global__ __launch_bounds__(256) void k_gemm_bf16(const short* __restrict__ A,
                                                   const short* __restrict__ Bt,
                                                   float* __restrict__ C,
                                                   int M, int N, int K) {
  __shared__ char lds[32768];   // As 16KB + Bs 16KB
  char* As = lds;
  char* Bs = lds + 16384;
  const int tid = threadIdx.x;
  const int w = tid >> 6, l = tid & 63;
  const int lq = l & 15, g = l >> 4;
  const int nx = N >> 7;
  const int bid = xcd_swz(blockIdx.x, nx * (M >> 7));
  const int m0 = (bid / nx) * 128, n0 = (bid % nx) * 128;
  const int wm = (w >> 1) * 64, wn = (w & 1) * 64;
  f32x4 acc[4][4] = {};

  const int nk = K >> 6;
  for (int kt = 0; kt < nk; ++kt) {
    const int k0 = kt * 64;
#pragma unroll
    for (int i = 0; i < 4; ++i) {
      int ch = (i * 4 + w) * 64 + l;          // 16B chunk id, 1024 per tile
      int r = ch >> 3, cc = ch & 7;
      int gc = cc ^ (r & 7);                  // XOR swizzle (involution)
      gload_lds16(A + (size_t)(m0 + r) * K + k0 + gc * 8, As + (i * 4 + w) * 1024);
      gload_lds16(Bt + (size_t)(n0 + r) * K + k0 + gc * 8, Bs + (i * 4 + w) * 1024);
    }
    __syncthreads();
#pragma unroll
    for (int kk = 0; kk < 2; ++kk) {
      bf16x8 af[4], bfr[4];
#pragma unroll
      for (int mi = 0; mi < 4; ++mi) {
        int row = wm + mi * 16 + lq;
        af[mi] = *(const bf16x8*)(As + row * 128 + (((kk * 4 + g) ^ (row & 7)) * 16));
      }
#pragma unroll
      for (int ni = 0; ni < 4; ++ni) {
        int row = wn + ni * 16 + lq;
        bfr[ni] = *(const bf16x8*)(Bs + row * 128 + (((kk * 4 + g) ^ (row & 7)) * 16));
      }
#pragma unroll
      for (int mi = 0; mi < 4; ++mi)
#pragma unroll
        for (int ni = 0; ni < 4; ++ni)
          acc[mi][ni] = __builtin_amdgcn_mfma_f32_16x16x32_bf16(af[mi], bfr[ni],
                                                                acc[mi][ni], 0, 0, 0);
    }
    __syncthreads();
  }
#pragma unroll
  for (int mi = 0; mi < 4; ++mi)
#pragma unroll
    for (int ni = 0; ni < 4; ++ni)
#pragma unroll
      for (int r = 0; r < 4; ++r) {
        int row = m0 + wm + mi * 16 + 4 * g + r;
        int col = n0 + wn + ni * 16 + lq;
        C[(size_t)row * N + col] = acc[mi][ni][r];
      }
}

// ---- fused QKV GEMM + RoPE + bf16 layout (verified), BK=64, XCD-swizzled ----
__global__ __launch_bounds__(256) void k_gemm_qkv_rope(const short* __restrict__ A,
                                                       const short* __restrict__ Bt,
                                                       const int* __restrict__ pos,
                                                       short* __restrict__ Qh,
                                                       short* __restrict__ Kh,
                                                       short* __restrict__ VT) {
  __shared__ char lds[32768];   // As 16KB + Bs 16KB
  char* As = lds;
  char* Bs = lds + 16384;
  const int tid = threadIdx.x;
  const int w = tid >> 6, l = tid & 63;
  const int lq = l & 15, g = l >> 4;
  const int bid = xcd_swz(blockIdx.x, (QKVW >> 7) * (TOK >> 7));
  const int hx = bid % (QKVW >> 7);
  const int m0 = (bid / (QKVW >> 7)) * 128, n0 = hx * 128;
  const int K = HID;
  f32x4 acc[2][8] = {};

  const int nk = K >> 6;
  for (int kt = 0; kt < nk; ++kt) {
    const int k0 = kt * 64;
#pragma unroll
    for (int i = 0; i < 4; ++i) {
      int ch = (i * 4 + w) * 64 + l;
      int r = ch >> 3, cc = ch & 7;
      int gc = cc ^ (r & 7);
      gload_lds16(A + (size_t)(m0 + r) * K + k0 + gc * 8, As + (i * 4 + w) * 1024);
      gload_lds16(Bt + (size_t)(n0 + r) * K + k0 + gc * 8, Bs + (i * 4 + w) * 1024);
    }
    __syncthreads();
#pragma unroll
    for (int kk = 0; kk < 2; ++kk) {
      bf16x8 af[2], bfr[8];
#pragma unroll
      for (int mi = 0; mi < 2; ++mi) {
        int row = w * 32 + mi * 16 + lq;
        af[mi] = *(const bf16x8*)(As + row * 128 + (((kk * 4 + g) ^ (row & 7)) * 16));
      }
#pragma unroll
      for (int ni = 0; ni < 8; ++ni) {
        int row = ni * 16 + lq;
        bfr[ni] = *(const bf16x8*)(Bs + row * 128 + (((kk * 4 + g) ^ (row & 7)) * 16));
      }
#pragma unroll
      for (int mi = 0; mi < 2; ++mi)
#pragma unroll
        for (int ni = 0; ni < 8; ++ni)
          acc[mi][ni] = __builtin_amdgcn_mfma_f32_16x16x32_bf16(af[mi], bfr[ni],
                                                                acc[mi][ni], 0, 0, 0);
    }
    __syncthreads();
  }

  const int b = m0 >> 11;                   // 128-row tile lies in one batch
  if (hx < 20) {
    const float qscale = 0.12751743920f;    // log2(e)/sqrt(128)
    const float sc = (hx < 16) ? qscale : 1.0f;
    short* dst = (hx < 16) ? (Qh + (size_t)(b * NH + hx) * SDIM * HD)
                           : (Kh + (size_t)(b * NKV + (hx - 16)) * SDIM * HD);
    // invf_rev[ni] = 10000^(-(ni*16+lq)/64) / (2*pi)
    float invf[4];
#pragma unroll
    for (int ni = 0; ni < 4; ++ni)
      invf[ni] = 0.15915494309f *
                 exp2_fast(-(float)(ni * 16 + lq) * (13.287712379549449f / 64.0f));
#pragma unroll
    for (int mi = 0; mi < 2; ++mi)
#pragma unroll
      for (int r = 0; r < 4; ++r) {
        int row = m0 + w * 32 + mi * 16 + 4 * g + r;
        int s = row & (SDIM - 1);
        float p = (float)pos[row];
        size_t hb = (size_t)s * HD;
#pragma unroll
        for (int ni = 0; ni < 4; ++ni) {
          float sn, cs;
          sincos_rev(p * invf[ni], &sn, &cs);
          float x1 = acc[mi][ni][r], x2 = acc[mi][ni + 4][r];
          dst[hb + ni * 16 + lq] = f2bf((x1 * cs - x2 * sn) * sc);
          dst[hb + ni * 16 + lq + 64] = f2bf((x2 * cs + x1 * sn) * sc);
        }
      }
  } else {
    const int hv = hx - 20;
    const int s00 = (m0 & (SDIM - 1)) + w * 32;
#pragma unroll
    for (int mi = 0; mi < 2; ++mi)
#pragma unroll
      for (int ni = 0; ni < 8; ++ni) {
        int d = ni * 16 + lq;
        int s0 = s00 + mi * 16 + 4 * g;
        size_t vb = ((size_t)(b * NKV + hv) * HD + d) * SDIM + s0;
        short4 ov;
        ov.x = f2bf(acc[mi][ni][0]); ov.y = f2bf(acc[mi][ni][1]);
        ov.z = f2bf(acc[mi][ni][2]); ov.w = f2bf(acc[mi][ni][3]);
        *(short4*)(VT + vb) = ov;
      }
  }
}

// ---- flash attention, causal GQA (round-11/15 verified best: ~89us) ----
// 4 waves x 32 q-rows, KVBLK=64, 32x32x16 MFMA. K/V double-buffered in LDS
// (64KB), 2-phase schedule. Interior tiles skip the causal mask. Log2-domain
// softmax (Q pre-scaled), defer-max, cvt_pk P-pack, setprio around MFMA.
__global__ __launch_bounds__(256, 2) void k_attn(const short* __restrict__ Qh,
                                                 const short* __restrict__ Kh,
                                                 const short* __restrict__ VT,
                                                 short* __restrict__ attn, int S) {
  __shared__ char lds[2][32768];            // per buf: K[64][256B] 16KB, V[128][128B] 16KB
  const int tid = threadIdx.x;
  const int w = tid >> 6, l = tid & 63;
  const int l31 = l & 31, hi = l >> 5;
  const int nqc = S / 128;                  // 16
  const int bid = blockIdx.x;
  const int b = bid / (NH * nqc);
  const int rem = bid % (NH * nqc);
  const int h = rem / nqc;
  const int qc = nqc - 1 - (rem % nqc);     // long blocks first
  const int q0 = qc * 128 + w * 32;
  const int kvh = h >> 2;
  const short* Qp = Qh + (size_t)(b * NH + h) * S * HD;
  const short* Kp = Kh + (size_t)(b * NKV + kvh) * S * HD;
  const short* Vp = VT + (size_t)(b * NKV + kvh) * HD * S;

  // Q B-frags: col=l31=q, k = kc*16 + hi*8 + e
  bf16x8 qf[8];
#pragma unroll
  for (int kc = 0; kc < 8; ++kc)
    qf[kc] = *(const bf16x8*)(Qp + (size_t)(q0 + l31) * HD + kc * 16 + hi * 8);

  f32x16 o[4] = {};   // O^T block d0: row=d-rel=(r&3)+8*(r>>2)+4*hi, col=q=l31
  float mrun = -1e30f, lrun = 0.f;
  const int qabs = q0 + l31;
  const int ntu = qc * 2 + 2;               // block-uniform 64-kv tile count

  // STAGE: K 1024 chunks [kr=id>>4][c16=id&15] swz c16^(kr&15) (2-way free);
  // V 1024 chunks [vr=id>>3][c8=id&7] swz c8^(vr&7).
#define STAGE(bufi, c0_)                                                          \
  {                                                                               \
    char* Kb = lds[bufi];                                                         \
    char* Vb = lds[bufi] + 16384;                                                 \
    _Pragma("unroll")                                                             \
    for (int i = 0; i < 4; ++i) {                                                 \
      int id = (i * 4 + w) * 64 + l;                                              \
      int kr = id >> 4, c16 = id & 15;                                            \
      gload_lds16(Kp + (size_t)((c0_) + kr) * HD + ((c16 ^ (kr & 15)) * 8),       \
                  Kb + (i * 4 + w) * 1024);                                       \
      int vr = id >> 3, c8 = id & 7;                                              \
      gload_lds16(Vp + (size_t)vr * S + (c0_) + ((c8 ^ (vr & 7)) * 8),            \
                  Vb + (i * 4 + w) * 1024);                                       \
    }                                                                             \
  }

  STAGE(0, 0);
  asm volatile("s_waitcnt vmcnt(0)" ::: "memory");
  __builtin_amdgcn_s_barrier();

  for (int c = 0; c < ntu; ++c) {
    const int c0 = c * 64;
    const int cur = c & 1;
    if (c + 1 < ntu) STAGE(cur ^ 1, c0 + 64);
    const char* Ks = lds[cur];
    const char* Vs = lds[cur] + 16384;

    // --- QK^T from LDS: two independent 32-kv subtiles ---
    f32x16 st[2];
    __builtin_amdgcn_s_setprio(1);
#pragma unroll
    for (int tt = 0; tt < 2; ++tt) {
      f32x16 s = {};
#pragma unroll
      for (int kc = 0; kc < 8; ++kc) {
        int kr = tt * 32 + l31;
        bf16x8 kf = *(const bf16x8*)(Ks + kr * 256 + (((kc * 2 + hi) ^ (l31 & 15)) * 16));
        s = __builtin_amdgcn_mfma_f32_32x32x16_bf16(kf, qf[kc], s, 0, 0, 0);
      }
      st[tt] = s;
    }
    __builtin_amdgcn_s_setprio(0);
    // --- mask (only on boundary tiles) + online softmax (log2 domain) ---
    float tmax = -1e30f;
    if (c0 + 64 <= q0) {                    // interior: no lane needs masking
#pragma unroll
      for (int tt = 0; tt < 2; ++tt)
#pragma unroll
        for (int r = 0; r < 16; ++r) tmax = fmaxf(tmax, st[tt][r]);
    } else {
#pragma unroll
      for (int tt = 0; tt < 2; ++tt)
#pragma unroll
        for (int r = 0; r < 16; ++r) {
          int kv = c0 + tt * 32 + (r & 3) + 8 * (r >> 2) + 4 * hi;
          float sv = (kv <= qabs) ? st[tt][r] : -1e30f;
          st[tt][r] = sv;
          tmax = fmaxf(tmax, sv);
        }
    }
    tmax = fmaxf(tmax, __shfl_xor(tmax, 32));
    if (!__all(tmax - mrun <= 8.0f)) {      // defer-max: rescale only on real growth
      float mnew = fmaxf(mrun, tmax);
      float fac = exp2_fast(mrun - mnew);
      lrun *= fac;
#pragma unroll
      for (int d0 = 0; d0 < 4; ++d0) o[d0] = o[d0] * fac;
      mrun = mnew;
    }
    float sum = 0.f;
#pragma unroll
    for (int tt = 0; tt < 2; ++tt)
#pragma unroll
      for (int r = 0; r < 16; ++r) {
        float e = exp2_fast(st[tt][r] - mrun);
        st[tt][r] = e;
        sum += e;
      }
    sum += __shfl_xor(sum, 32);
    lrun += sum;
    // --- P -> B-frags (packed-word lane-half exchange) + PV from LDS V ---
    __builtin_amdgcn_s_setprio(1);
#pragma unroll
    for (int j = 0; j < 4; ++j) {
      const int tt = j >> 1, kc = j & 1;
      uint32_t W0 = (uint32_t)(uint16_t)f2bf(st[tt][8 * kc + 0]) |
                    ((uint32_t)(uint16_t)f2bf(st[tt][8 * kc + 1]) << 16);
      uint32_t W1 = (uint32_t)(uint16_t)f2bf(st[tt][8 * kc + 2]) |
                    ((uint32_t)(uint16_t)f2bf(st[tt][8 * kc + 3]) << 16);
      uint32_t W2 = (uint32_t)(uint16_t)f2bf(st[tt][8 * kc + 4]) |
                    ((uint32_t)(uint16_t)f2bf(st[tt][8 * kc + 5]) << 16);
      uint32_t W3 = (uint32_t)(uint16_t)f2bf(st[tt][8 * kc + 6]) |
                    ((uint32_t)(uint16_t)f2bf(st[tt][8 * kc + 7]) << 16);
      uint32_t Y0 = __shfl_xor(hi ? W0 : W2, 32);
      uint32_t Y1 = __shfl_xor(hi ? W1 : W3, 32);
      union { uint32_t u[4]; bf16x8 v; } pu;
      pu.u[0] = hi ? Y0 : W0;
      pu.u[1] = hi ? Y1 : W1;
      pu.u[2] = hi ? W2 : Y0;
      pu.u[3] = hi ? W3 : Y1;
#pragma unroll
      for (int d0 = 0; d0 < 4; ++d0) {
        int vr = d0 * 32 + l31;
        bf16x8 vf = *(const bf16x8*)(Vs + vr * 128 + (((j * 2 + hi) ^ (vr & 7)) * 16));
        o[d0] = __builtin_amdgcn_mfma_f32_32x32x16_bf16(vf, pu.v, o[d0], 0, 0, 0);
      }
    }
    __builtin_amdgcn_s_setprio(0);
    asm volatile("s_waitcnt vmcnt(0)" ::: "memory");
    __builtin_amdgcn_s_barrier();
  }
#undef STAGE
  // --- normalize + store: O^T -> attn[q][h*HD+d]; per-lane inv (q=l31) ---
  float inv = 1.0f / lrun;
  size_t rowb = (size_t)(b * S + q0 + l31) * QSZ + h * HD;
#pragma unroll
  for (int d0 = 0; d0 < 4; ++d0)
#pragma unroll
    for (int gq = 0; gq < 4; ++gq) {        // drel group: 8*gq + 4*hi + (0..3)
      short4 ov;
      ov.x = f2bf(o[d0][4 * gq + 0] * inv);
      ov.y = f2bf(o[d0][4 * gq + 1] * inv);
      ov.z = f2bf(o[d0][4 * gq + 2] * inv);
      ov.w = f2bf(o[d0][4 * gq + 3] * inv);
      *(short4*)(attn + rowb + d0 * 32 + 8 * gq + 4 * hi) = ov;
    }
}

extern "C" void kernel_launch(void* const* d_in, const int* in_sizes, int n_in,
                              void* d_out, int out_size, void* d_ws, size_t ws_size,
                              hipStream_t stream) {
  const int* positions = (const int*)d_in[0];
  const float* hidden = (const float*)d_in[1];
  const float* w_qkv = (const float*)d_in[2];
  const float* w_o = (const float*)d_in[3];
  float* out = (float*)d_out;

  char* ws = (char*)d_ws;
  short* X     = (short*)(ws);                    // 4096x2048 bf16
  short* WqkvT = (short*)(ws + 16777216);         // 3072x2048 bf16
  short* WoT   = (short*)(ws + 29360128);         // 2048x2048 bf16
  short* Qh    = (short*)(ws + 88080384);         // [2][16][2048][128]
  short* Kh    = (short*)(ws + 104857600);        // [2][4][2048][128]
  short* VT    = (short*)(ws + 109051904);        // [2][4][128][2048]
  short* ATT   = (short*)(ws + 113246208);        // [4096][2048] bf16

  k_prep<<<10752, 256, 0, stream>>>(hidden, w_qkv, w_o, X, WqkvT, WoT);
  k_gemm_qkv_rope<<<(QKVW / 128) * (TOK / 128), 256, 0, stream>>>(X, WqkvT, positions,
                                                                  Qh, Kh, VT);
  k_attn<<<BDIM * NH * (SDIM / 128), 256, 0, stream>>>(Qh, Kh, VT, ATT, SDIM);
  k_gemm_bf16<<<(HID / 128) * (TOK / 128), 256, 0, stream>>>(ATT, WoT, out, TOK, HID, QSZ);
}

// Round 17
// 217.469 us; speedup vs baseline: 1.0383x; 1.0383x over previous
//
#include <hip/hip_runtime.h>
#include <hip/hip_bf16.h>
#include <stdint.h>

// ---- problem constants ----
#define BDIM 2
#define SDIM 2048
#define HID 2048
#define NH 16
#define NKV 4
#define HD 128
#define QSZ 2048
#define KVSZ 512
#define QKVW 3072          // QSZ + 2*KVSZ
#define TOK (BDIM*SDIM)    // 4096

typedef __attribute__((ext_vector_type(8))) short bf16x8;
typedef __attribute__((ext_vector_type(4))) float f32x4;
typedef __attribute__((ext_vector_type(16))) float f32x16;

__device__ __forceinline__ short f2bf(float f) {
  return (short)__bfloat16_as_ushort(__float2bfloat16(f));   // RNE; pairs fuse to v_cvt_pk_bf16_f32
}

// 2^x via the HW transcendental (no __exp2f in this toolchain's headers)
__device__ __forceinline__ float exp2_fast(float x) {
  float r;
  asm("v_exp_f32 %0, %1" : "=v"(r) : "v"(x));
  return r;
}

// sin/cos with input in REVOLUTIONS (v_sin/v_cos native domain; fract-reduce first)
__device__ __forceinline__ void sincos_rev(float rev, float* sn, float* cs) {
  float fr, s, c;
  asm("v_fract_f32 %0, %1" : "=v"(fr) : "v"(rev));
  asm("v_sin_f32 %0, %1" : "=v"(s) : "v"(fr));
  asm("v_cos_f32 %0, %1" : "=v"(c) : "v"(fr));
  *sn = s; *cs = c;
}

// XCD-aware block swizzle (T1, m157 form; requires nwg % 8 == 0)
__device__ __forceinline__ int xcd_swz(int orig, int nwg) {
  int cpx = nwg >> 3;
  return (orig & 7) * cpx + (orig >> 3);
}

__device__ __forceinline__ void gload_lds16(const void* g, void* lds) {
  __builtin_amdgcn_global_load_lds(
      (const __attribute__((address_space(1))) void*)g,
      (__attribute__((address_space(3))) void*)lds, 16, 0, 0);
}

// ---- fused prep: hidden f32->bf16 (blocks 0..8191), w_qkv transpose
// (blocks 8192..9727, 48x32 tiles), w_o transpose (blocks 9728..10751, 32x32) ----
__global__ __launch_bounds__(256) void k_prep(const float* __restrict__ hidden,
                                              const float* __restrict__ w_qkv,
                                              const float* __restrict__ w_o,
                                              short* __restrict__ X,
                                              short* __restrict__ WqkvT,
                                              short* __restrict__ WoT) {
  __shared__ short tile[64][65];
  const int bid = blockIdx.x;
  const int t = threadIdx.x;
  if (bid < 8192) {
    int i = (bid * 256 + t) * 4;
    float4 v = *(const float4*)(hidden + i);
    short4 o; o.x = f2bf(v.x); o.y = f2bf(v.y); o.z = f2bf(v.z); o.w = f2bf(v.w);
    *(short4*)(X + i) = o;
    return;
  }
  const float* in; short* out; int R, C, bx, by;
  if (bid < 9728) {
    int tt = bid - 8192; in = w_qkv; out = WqkvT; R = HID; C = QKVW;
    bx = tt % 48; by = tt / 48;
  } else {
    int tt = bid - 9728; in = w_o; out = WoT; R = QSZ; C = HID;
    bx = tt & 31; by = tt >> 5;
  }
  int k0 = by * 64, n0 = bx * 64;
#pragma unroll
  for (int i = 0; i < 16; ++i) {
    int idx = i * 256 + t;
    int kk = idx >> 6, nn = idx & 63;
    tile[kk][nn] = f2bf(in[(size_t)(k0 + kk) * C + n0 + nn]);
  }
  __syncthreads();
#pragma unroll
  for (int i = 0; i < 16; ++i) {
    int idx = i * 256 + t;
    int nn = idx >> 6, kk = idx & 63;
    out[(size_t)(n0 + nn) * R + k0 + kk] = tile[kk][nn];
  }
}

// ---- bf16 GEMM: C[M][N] f32 = A[M][K] * Bt[N][K]^T  (m97 structure, BK=32) ----
// 1D grid, XCD-swizzled: neighbor tiles land on the same XCD's L2.
__global__ __launch_bounds__(256) void k_gemm_bf16(const short* __restrict__ A,
                                                   const short* __restrict__ Bt,
                                                   float* __restrict__ C,
                                                   int M, int N, int K) {
  __shared__ char lds[128 * 32 * 2 * 2];   // As 8KB + Bs 8KB
  char* As = lds;
  char* Bs = lds + 8192;
  const int tid = threadIdx.x;
  const int w = tid >> 6, l = tid & 63;
  const int lq = l & 15, g = l >> 4;
  const int nx = N >> 7;
  const int bid = xcd_swz(blockIdx.x, nx * (M >> 7));
  const int m0 = (bid / nx) * 128, n0 = (bid % nx) * 128;
  const int wm = (w >> 1) * 64, wn = (w & 1) * 64;
  f32x4 acc[4][4] = {};

  const int nk = K >> 5;
  for (int kt = 0; kt < nk; ++kt) {
    const int k0 = kt * 32;
#pragma unroll
    for (int i = 0; i < 2; ++i) {
      int ch = (w + 4 * i) * 64 + l;          // 16B chunk id in tile
      int r = ch >> 2, cc = ch & 3;
      int gc = cc ^ ((r >> 1) & 3);           // XOR swizzle (involution)
      gload_lds16(A + (size_t)(m0 + r) * K + k0 + gc * 8, As + (w + 4 * i) * 1024);
      gload_lds16(Bt + (size_t)(n0 + r) * K + k0 + gc * 8, Bs + (w + 4 * i) * 1024);
    }
    __syncthreads();
    bf16x8 af[4], bfr[4];
#pragma unroll
    for (int mi = 0; mi < 4; ++mi) {
      int row = wm + mi * 16 + lq;
      af[mi] = *(const bf16x8*)(As + row * 64 + ((g ^ ((row >> 1) & 3)) * 16));
    }
#pragma unroll
    for (int ni = 0; ni < 4; ++ni) {
      int row = wn + ni * 16 + lq;
      bfr[ni] = *(const bf16x8*)(Bs + row * 64 + ((g ^ ((row >> 1) & 3)) * 16));
    }
#pragma unroll
    for (int mi = 0; mi < 4; ++mi)
#pragma unroll
      for (int ni = 0; ni < 4; ++ni)
        acc[mi][ni] = __builtin_amdgcn_mfma_f32_16x16x32_bf16(af[mi], bfr[ni],
                                                              acc[mi][ni], 0, 0, 0);
    __syncthreads();
  }
#pragma unroll
  for (int mi = 0; mi < 4; ++mi)
#pragma unroll
    for (int ni = 0; ni < 4; ++ni)
#pragma unroll
      for (int r = 0; r < 4; ++r) {
        int row = m0 + wm + mi * 16 + 4 * g + r;
        int col = n0 + wn + ni * 16 + lq;
        C[(size_t)row * N + col] = acc[mi][ni][r];
      }
}

// ---- fused QKV GEMM + RoPE + bf16 layout (verified rounds 8/11/15), BK=32 ----
__global__ __launch_bounds__(256) void k_gemm_qkv_rope(const short* __restrict__ A,
                                                       const short* __restrict__ Bt,
                                                       const int* __restrict__ pos,
                                                       short* __restrict__ Qh,
                                                       short* __restrict__ Kh,
                                                       short* __restrict__ VT) {
  __shared__ char lds[128 * 32 * 2 * 2];   // As 8KB + Bs 8KB
  char* As = lds;
  char* Bs = lds + 8192;
  const int tid = threadIdx.x;
  const int w = tid >> 6, l = tid & 63;
  const int lq = l & 15, g = l >> 4;
  const int bid = xcd_swz(blockIdx.x, (QKVW >> 7) * (TOK >> 7));
  const int hx = bid % (QKVW >> 7);
  const int m0 = (bid / (QKVW >> 7)) * 128, n0 = hx * 128;
  const int K = HID;
  f32x4 acc[2][8] = {};

  const int nk = K >> 5;
  for (int kt = 0; kt < nk; ++kt) {
    const int k0 = kt * 32;
#pragma unroll
    for (int i = 0; i < 2; ++i) {
      int ch = (w + 4 * i) * 64 + l;
      int r = ch >> 2, cc = ch & 3;
      int gc = cc ^ ((r >> 1) & 3);
      gload_lds16(A + (size_t)(m0 + r) * K + k0 + gc * 8, As + (w + 4 * i) * 1024);
      gload_lds16(Bt + (size_t)(n0 + r) * K + k0 + gc * 8, Bs + (w + 4 * i) * 1024);
    }
    __syncthreads();
    bf16x8 af[2], bfr[8];
#pragma unroll
    for (int mi = 0; mi < 2; ++mi) {
      int row = w * 32 + mi * 16 + lq;
      af[mi] = *(const bf16x8*)(As + row * 64 + ((g ^ ((row >> 1) & 3)) * 16));
    }
#pragma unroll
    for (int ni = 0; ni < 8; ++ni) {
      int row = ni * 16 + lq;
      bfr[ni] = *(const bf16x8*)(Bs + row * 64 + ((g ^ ((row >> 1) & 3)) * 16));
    }
#pragma unroll
    for (int mi = 0; mi < 2; ++mi)
#pragma unroll
      for (int ni = 0; ni < 8; ++ni)
        acc[mi][ni] = __builtin_amdgcn_mfma_f32_16x16x32_bf16(af[mi], bfr[ni],
                                                              acc[mi][ni], 0, 0, 0);
    __syncthreads();
  }

  const int b = m0 >> 11;                   // 128-row tile lies in one batch
  if (hx < 20) {
    const float qscale = 0.12751743920f;    // log2(e)/sqrt(128)
    const float sc = (hx < 16) ? qscale : 1.0f;
    short* dst = (hx < 16) ? (Qh + (size_t)(b * NH + hx) * SDIM * HD)
                           : (Kh + (size_t)(b * NKV + (hx - 16)) * SDIM * HD);
    // invf_rev[ni] = 10000^(-(ni*16+lq)/64) / (2*pi)
    float invf[4];
#pragma unroll
    for (int ni = 0; ni < 4; ++ni)
      invf[ni] = 0.15915494309f *
                 exp2_fast(-(float)(ni * 16 + lq) * (13.287712379549449f / 64.0f));
#pragma unroll
    for (int mi = 0; mi < 2; ++mi)
#pragma unroll
      for (int r = 0; r < 4; ++r) {
        int row = m0 + w * 32 + mi * 16 + 4 * g + r;
        int s = row & (SDIM - 1);
        float p = (float)pos[row];
        size_t hb = (size_t)s * HD;
#pragma unroll
        for (int ni = 0; ni < 4; ++ni) {
          float sn, cs;
          sincos_rev(p * invf[ni], &sn, &cs);
          float x1 = acc[mi][ni][r], x2 = acc[mi][ni + 4][r];
          dst[hb + ni * 16 + lq] = f2bf((x1 * cs - x2 * sn) * sc);
          dst[hb + ni * 16 + lq + 64] = f2bf((x2 * cs + x1 * sn) * sc);
        }
      }
  } else {
    const int hv = hx - 20;
    const int s00 = (m0 & (SDIM - 1)) + w * 32;
#pragma unroll
    for (int mi = 0; mi < 2; ++mi)
#pragma unroll
      for (int ni = 0; ni < 8; ++ni) {
        int d = ni * 16 + lq;
        int s0 = s00 + mi * 16 + 4 * g;
        size_t vb = ((size_t)(b * NKV + hv) * HD + d) * SDIM + s0;
        short4 ov;
        ov.x = f2bf(acc[mi][ni][0]); ov.y = f2bf(acc[mi][ni][1]);
        ov.z = f2bf(acc[mi][ni][2]); ov.w = f2bf(acc[mi][ni][3]);
        *(short4*)(VT + vb) = ov;
      }
  }
}

// ---- flash attention, causal GQA (round-11/15 verified best: ~89us) ----
// 4 waves x 32 q-rows, KVBLK=64, 32x32x16 MFMA. K/V double-buffered in LDS
// (64KB), 2-phase schedule. Interior tiles skip the causal mask. Log2-domain
// softmax (Q pre-scaled), defer-max, cvt_pk P-pack, setprio around MFMA.
__global__ __launch_bounds__(256, 2) void k_attn(const short* __restrict__ Qh,
                                                 const short* __restrict__ Kh,
                                                 const short* __restrict__ VT,
                                                 short* __restrict__ attn, int S) {
  __shared__ char lds[2][32768];            // per buf: K[64][256B] 16KB, V[128][128B] 16KB
  const int tid = threadIdx.x;
  const int w = tid >> 6, l = tid & 63;
  const int l31 = l & 31, hi = l >> 5;
  const int nqc = S / 128;                  // 16
  const int bid = blockIdx.x;
  const int b = bid / (NH * nqc);
  const int rem = bid % (NH * nqc);
  const int h = rem / nqc;
  const int qc = nqc - 1 - (rem % nqc);     // long blocks first
  const int q0 = qc * 128 + w * 32;
  const int kvh = h >> 2;
  const short* Qp = Qh + (size_t)(b * NH + h) * S * HD;
  const short* Kp = Kh + (size_t)(b * NKV + kvh) * S * HD;
  const short* Vp = VT + (size_t)(b * NKV + kvh) * HD * S;

  // Q B-frags: col=l31=q, k = kc*16 + hi*8 + e
  bf16x8 qf[8];
#pragma unroll
  for (int kc = 0; kc < 8; ++kc)
    qf[kc] = *(const bf16x8*)(Qp + (size_t)(q0 + l31) * HD + kc * 16 + hi * 8);

  f32x16 o[4] = {};   // O^T block d0: row=d-rel=(r&3)+8*(r>>2)+4*hi, col=q=l31
  float mrun = -1e30f, lrun = 0.f;
  const int qabs = q0 + l31;
  const int ntu = qc * 2 + 2;               // block-uniform 64-kv tile count

  // STAGE: K 1024 chunks [kr=id>>4][c16=id&15] swz c16^(kr&15) (2-way free);
  // V 1024 chunks [vr=id>>3][c8=id&7] swz c8^(vr&7).
#define STAGE(bufi, c0_)                                                          \
  {                                                                               \
    char* Kb = lds[bufi];                                                         \
    char* Vb = lds[bufi] + 16384;                                                 \
    _Pragma("unroll")                                                             \
    for (int i = 0; i < 4; ++i) {                                                 \
      int id = (i * 4 + w) * 64 + l;                                              \
      int kr = id >> 4, c16 = id & 15;                                            \
      gload_lds16(Kp + (size_t)((c0_) + kr) * HD + ((c16 ^ (kr & 15)) * 8),       \
                  Kb + (i * 4 + w) * 1024);                                       \
      int vr = id >> 3, c8 = id & 7;                                              \
      gload_lds16(Vp + (size_t)vr * S + (c0_) + ((c8 ^ (vr & 7)) * 8),            \
                  Vb + (i * 4 + w) * 1024);                                       \
    }                                                                             \
  }

  STAGE(0, 0);
  asm volatile("s_waitcnt vmcnt(0)" ::: "memory");
  __builtin_amdgcn_s_barrier();

  for (int c = 0; c < ntu; ++c) {
    const int c0 = c * 64;
    const int cur = c & 1;
    if (c + 1 < ntu) STAGE(cur ^ 1, c0 + 64);
    const char* Ks = lds[cur];
    const char* Vs = lds[cur] + 16384;

    // --- QK^T from LDS: two independent 32-kv subtiles ---
    f32x16 st[2];
    __builtin_amdgcn_s_setprio(1);
#pragma unroll
    for (int tt = 0; tt < 2; ++tt) {
      f32x16 s = {};
#pragma unroll
      for (int kc = 0; kc < 8; ++kc) {
        int kr = tt * 32 + l31;
        bf16x8 kf = *(const bf16x8*)(Ks + kr * 256 + (((kc * 2 + hi) ^ (l31 & 15)) * 16));
        s = __builtin_amdgcn_mfma_f32_32x32x16_bf16(kf, qf[kc], s, 0, 0, 0);
      }
      st[tt] = s;
    }
    __builtin_amdgcn_s_setprio(0);
    // --- mask (only on boundary tiles) + online softmax (log2 domain) ---
    float tmax = -1e30f;
    if (c0 + 64 <= q0) {                    // interior: no lane needs masking
#pragma unroll
      for (int tt = 0; tt < 2; ++tt)
#pragma unroll
        for (int r = 0; r < 16; ++r) tmax = fmaxf(tmax, st[tt][r]);
    } else {
#pragma unroll
      for (int tt = 0; tt < 2; ++tt)
#pragma unroll
        for (int r = 0; r < 16; ++r) {
          int kv = c0 + tt * 32 + (r & 3) + 8 * (r >> 2) + 4 * hi;
          float sv = (kv <= qabs) ? st[tt][r] : -1e30f;
          st[tt][r] = sv;
          tmax = fmaxf(tmax, sv);
        }
    }
    tmax = fmaxf(tmax, __shfl_xor(tmax, 32));
    if (!__all(tmax - mrun <= 8.0f)) {      // defer-max: rescale only on real growth
      float mnew = fmaxf(mrun, tmax);
      float fac = exp2_fast(mrun - mnew);
      lrun *= fac;
#pragma unroll
      for (int d0 = 0; d0 < 4; ++d0) o[d0] = o[d0] * fac;
      mrun = mnew;
    }
    float sum = 0.f;
#pragma unroll
    for (int tt = 0; tt < 2; ++tt)
#pragma unroll
      for (int r = 0; r < 16; ++r) {
        float e = exp2_fast(st[tt][r] - mrun);
        st[tt][r] = e;
        sum += e;
      }
    sum += __shfl_xor(sum, 32);
    lrun += sum;
    // --- P -> B-frags (packed-word lane-half exchange) + PV from LDS V ---
    __builtin_amdgcn_s_setprio(1);
#pragma unroll
    for (int j = 0; j < 4; ++j) {
      const int tt = j >> 1, kc = j & 1;
      uint32_t W0 = (uint32_t)(uint16_t)f2bf(st[tt][8 * kc + 0]) |
                    ((uint32_t)(uint16_t)f2bf(st[tt][8 * kc + 1]) << 16);
      uint32_t W1 = (uint32_t)(uint16_t)f2bf(st[tt][8 * kc + 2]) |
                    ((uint32_t)(uint16_t)f2bf(st[tt][8 * kc + 3]) << 16);
      uint32_t W2 = (uint32_t)(uint16_t)f2bf(st[tt][8 * kc + 4]) |
                    ((uint32_t)(uint16_t)f2bf(st[tt][8 * kc + 5]) << 16);
      uint32_t W3 = (uint32_t)(uint16_t)f2bf(st[tt][8 * kc + 6]) |
                    ((uint32_t)(uint16_t)f2bf(st[tt][8 * kc + 7]) << 16);
      uint32_t Y0 = __shfl_xor(hi ? W0 : W2, 32);
      uint32_t Y1 = __shfl_xor(hi ? W1 : W3, 32);
      union { uint32_t u[4]; bf16x8 v; } pu;
      pu.u[0] = hi ? Y0 : W0;
      pu.u[1] = hi ? Y1 : W1;
      pu.u[2] = hi ? W2 : Y0;
      pu.u[3] = hi ? W3 : Y1;
#pragma unroll
      for (int d0 = 0; d0 < 4; ++d0) {
        int vr = d0 * 32 + l31;
        bf16x8 vf = *(const bf16x8*)(Vs + vr * 128 + (((j * 2 + hi) ^ (vr & 7)) * 16));
        o[d0] = __builtin_amdgcn_mfma_f32_32x32x16_bf16(vf, pu.v, o[d0], 0, 0, 0);
      }
    }
    __builtin_amdgcn_s_setprio(0);
    asm volatile("s_waitcnt vmcnt(0)" ::: "memory");
    __builtin_amdgcn_s_barrier();
  }
#undef STAGE
  // --- normalize + store: O^T -> attn[q][h*HD+d]; per-lane inv (q=l31) ---
  float inv = 1.0f / lrun;
  size_t rowb = (size_t)(b * S + q0 + l31) * QSZ + h * HD;
#pragma unroll
  for (int d0 = 0; d0 < 4; ++d0)
#pragma unroll
    for (int gq = 0; gq < 4; ++gq) {        // drel group: 8*gq + 4*hi + (0..3)
      short4 ov;
      ov.x = f2bf(o[d0][4 * gq + 0] * inv);
      ov.y = f2bf(o[d0][4 * gq + 1] * inv);
      ov.z = f2bf(o[d0][4 * gq + 2] * inv);
      ov.w = f2bf(o[d0][4 * gq + 3] * inv);
      *(short4*)(attn + rowb + d0 * 32 + 8 * gq + 4 * hi) = ov;
    }
}

extern "C" void kernel_launch(void* const* d_in, const int* in_sizes, int n_in,
                              void* d_out, int out_size, void* d_ws, size_t ws_size,
                              hipStream_t stream) {
  const int* positions = (const int*)d_in[0];
  const float* hidden = (const float*)d_in[1];
  const float* w_qkv = (const float*)d_in[2];
  const float* w_o = (const float*)d_in[3];
  float* out = (float*)d_out;

  char* ws = (char*)d_ws;
  short* X     = (short*)(ws);                    // 4096x2048 bf16
  short* WqkvT = (short*)(ws + 16777216);         // 3072x2048 bf16
  short* WoT   = (short*)(ws + 29360128);         // 2048x2048 bf16
  short* Qh    = (short*)(ws + 88080384);         // [2][16][2048][128]
  short* Kh    = (short*)(ws + 104857600);        // [2][4][2048][128]
  short* VT    = (short*)(ws + 109051904);        // [2][4][128][2048]
  short* ATT   = (short*)(ws + 113246208);        // [4096][2048] bf16

  k_prep<<<10752, 256, 0, stream>>>(hidden, w_qkv, w_o, X, WqkvT, WoT);
  k_gemm_qkv_rope<<<(QKVW / 128) * (TOK / 128), 256, 0, stream>>>(X, WqkvT, positions,
                                                                  Qh, Kh, VT);
  k_attn<<<BDIM * NH * (SDIM / 128), 256, 0, stream>>>(Qh, Kh, VT, ATT, SDIM);
  k_gemm_bf16<<<(HID / 128) * (TOK / 128), 256, 0, stream>>>(ATT, WoT, out, TOK, HID, QSZ);
}